// Round 12
// baseline (263.753 us; speedup 1.0000x reference)
//
#include <hip/hip_runtime.h>

// Problem constants (match reference file)
#define B_   2
#define S_   2048
#define D_   512
#define H_   8
#define DK_  64
#define FF_  2048
#define EPS_ 1e-3f
#define QS_  1536   // fused QKV output width (q|k|v)

typedef __bf16 bf16;
typedef __bf16 bf16x4 __attribute__((ext_vector_type(4)));
typedef __bf16 bf16x8 __attribute__((ext_vector_type(8)));
typedef float  f32x4  __attribute__((ext_vector_type(4)));

// async global->LDS, 16B per lane, LDS dest = wave-uniform base + lane*16
__device__ __forceinline__ void gload16(const bf16* g, bf16* l) {
  __builtin_amdgcn_global_load_lds(
      (__attribute__((address_space(1))) void*)g,
      (__attribute__((address_space(3))) void*)l, 16, 0, 0);
}

// ---------------------------------------------------------------------------
// Fused prep kernel (1 launch): 1D grid, range-decoded.
//  [0,1024)    : transpose+split Wq/Wk/Wv/Wo (512x512 each)
//  [1024,2048) : transpose+split W1 (512x2048 -> [2048][512])
//  [2048,3072) : transpose+split W2 (2048x512 -> [512][2048])
//  [3072,5120) : mask_split (x -> xm hi/lo)
//  [5120,5126) : pack qkv bias
// ---------------------------------------------------------------------------
struct PrepArgs {
  const float* w[4];      // Wq, Wk, Wv, Wo
  bf16* thi[4];
  bf16* tlo[4];
  int rowOff[4];
  const float* W1; bf16* W1hi; bf16* W1lo;
  const float* W2; bf16* W2hi; bf16* W2lo;
  const float* x; const int* lengths; bf16* xhi; bf16* xlo;
  const float* bq; const float* bk; const float* bv; float* bqkv;
};

__device__ __forceinline__ void transpose_tile(const float* W, int K, int N,
                                               bf16* Thi, bf16* Tlo,
                                               int n0, int k0, int rowOff,
                                               float (*tl)[33], int t) {
  const int tx = t & 31, ty = t >> 5;  // 32 x 8
#pragma unroll
  for (int r = 0; r < 32; r += 8)
    tl[r + ty][tx] = W[(size_t)(k0 + r + ty) * N + n0 + tx];
  __syncthreads();
#pragma unroll
  for (int r = 0; r < 32; r += 8) {
    const int n = r + ty;
    const float v = tl[tx][n];  // stride-33 -> conflict-free
    const bf16 h = (bf16)v;
    const size_t o = (size_t)(rowOff + n0 + n) * K + k0 + tx;
    Thi[o] = h;
    Tlo[o] = (bf16)(v - (float)h);
  }
}

__global__ __launch_bounds__(256) void prep_kernel(PrepArgs a) {
  __shared__ float tl[32][33];
  const int id = blockIdx.x;
  const int t = threadIdx.x;
  if (id < 1024) {  // 4x 512x512 transpose+split
    const int wsel = id >> 8, rem = id & 255;
    transpose_tile(a.w[wsel], 512, 512, a.thi[wsel], a.tlo[wsel],
                   (rem & 15) * 32, (rem >> 4) * 32, a.rowOff[wsel], tl, t);
  } else if (id < 2048) {  // W1: [512][2048] -> T[2048][512]
    const int rem = id - 1024;
    transpose_tile(a.W1, 512, 2048, a.W1hi, a.W1lo,
                   (rem & 63) * 32, (rem >> 6) * 32, 0, tl, t);
  } else if (id < 3072) {  // W2: [2048][512] -> T[512][2048]
    const int rem = id - 2048;
    transpose_tile(a.W2, 2048, 512, a.W2hi, a.W2lo,
                   (rem & 15) * 32, (rem >> 4) * 32, 0, tl, t);
  } else if (id < 5120) {  // mask_split: one float4 per thread
    const int idx = (id - 3072) * 256 + t;
    const int d4 = D_ / 4;
    const int s = (idx / d4) & (S_ - 1);
    const int b = idx / (d4 * S_);
    float4 v = reinterpret_cast<const float4*>(a.x)[idx];
    if (s >= a.lengths[b]) { v.x = 0.f; v.y = 0.f; v.z = 0.f; v.w = 0.f; }
    const float vv[4] = {v.x, v.y, v.z, v.w};
    bf16x4 h, l;
#pragma unroll
    for (int c = 0; c < 4; ++c) {
      const bf16 hh = (bf16)vv[c];
      h[c] = hh;
      l[c] = (bf16)(vv[c] - (float)hh);
    }
    reinterpret_cast<bf16x4*>(a.xhi)[idx] = h;
    reinterpret_cast<bf16x4*>(a.xlo)[idx] = l;
  } else {  // pack bias
    const int i = (id - 5120) * 256 + t;
    if (i < 1536)
      a.bqkv[i] = (i < 512) ? a.bq[i] : (i < 1024) ? a.bk[i - 512] : a.bv[i - 1024];
  }
}

// ---------------------------------------------------------------------------
// Split-bf16 MFMA GEMM with 2-PHASE SOFTWARE PIPELINE (T3/T4 minimum recipe):
// double-buffered LDS; STAGE(next) issued BEFORE compute(cur); exactly ONE
// barrier per K-step. Safety: reads of buf B in iter k-1 are lgkm-drained at
// the iter-(k-1) barrier (compiler inserts lgkmcnt(0)+vmcnt(0) before
// s_barrier), so iter-k STAGE into B can't race them; iter-k+1 reads of B
// follow the iter-k barrier whose vmcnt(0) drains the STAGE.
// 128 x BN tile, BK=32, 256 thr = 4 waves (2x2). 3 MFMA products per acc.
// OPERAND-SWAPPED epilogue: lane holds C[row=mtile+fr][cols ntile+fg*4..+3].
// Split-K: s=1 -> C2 (no bias); downstream LN sums partials.
// ---------------------------------------------------------------------------
enum { EPI_BIAS_RELU = 2, EPI_PART = 4, EPI_QKV = 5 };

template <int EPI, bool SPLIT, int BN>
__global__ __launch_bounds__(256) void gemm_kernel(
    const bf16* __restrict__ Ahi, const bf16* __restrict__ Alo,
    const bf16* __restrict__ Bhi, const bf16* __restrict__ Blo,
    const float* __restrict__ bias,
    float* __restrict__ C, float* __restrict__ C2,
    bf16* __restrict__ Chi, bf16* __restrict__ Clo,
    int K, int ldc, int nx, int mn, int ksplit) {
  constexpr int NR = BN / 32;  // n-frags per wave
  __shared__ __align__(16) bf16 As[2][2][128][32];  // [buf][hi/lo][row][k]
  __shared__ __align__(16) bf16 Bs[2][2][BN][32];
  const int t = threadIdx.x;

  const int nwg = gridDim.x;
  const int chunk = nwg >> 3;
  const int virt = (blockIdx.x & 7) * chunk + (blockIdx.x >> 3);
  const int s = virt / mn;
  const int v2 = virt - s * mn;
  const int m0 = (v2 / nx) * 128, n0 = (v2 % nx) * BN;
  const int kb = s * ksplit;

  const int lane = t & 63, wv = t >> 6;
  const int fr = lane & 15, fg = lane >> 4;
  const int wm = (wv >> 1) * 64, wn = (wv & 1) * (BN / 2);
  const int sr = lane >> 2, sslot = lane & 3;  // staging: 16 rows x 4 chunks

  f32x4 acc[4][NR] = {};

  const bf16* gAh = Ahi + (size_t)m0 * K + kb;
  const bf16* gAl = Alo + (size_t)m0 * K + kb;
  const bf16* gBh = Bhi + (size_t)n0 * K + kb;
  const bf16* gBl = Blo + (size_t)n0 * K + kb;

  auto stage = [&](int buf, int k0) {
#pragma unroll
    for (int q = 0; q < 2; ++q) {  // A: 32 rows per wave
      const int r = wv * 32 + q * 16 + sr;
      const size_t go = (size_t)r * K + k0 + sslot * 8;
      gload16(gAh + go, &As[buf][0][wv * 32 + q * 16][0]);
      gload16(gAl + go, &As[buf][1][wv * 32 + q * 16][0]);
    }
    if constexpr (BN == 128) {
#pragma unroll
      for (int q = 0; q < 2; ++q) {
        const int r = wv * 32 + q * 16 + sr;
        const size_t go = (size_t)r * K + k0 + sslot * 8;
        gload16(gBh + go, &Bs[buf][0][wv * 32 + q * 16][0]);
        gload16(gBl + go, &Bs[buf][1][wv * 32 + q * 16][0]);
      }
    } else {  // BN == 64: 16 rows per wave
      const int r = wv * 16 + sr;
      const size_t go = (size_t)r * K + k0 + sslot * 8;
      gload16(gBh + go, &Bs[buf][0][wv * 16][0]);
      gload16(gBl + go, &Bs[buf][1][wv * 16][0]);
    }
  };

  const int nt = ksplit >> 5;  // K-steps of 32
  stage(0, 0);
  __syncthreads();  // vmcnt(0) drain: buf0 ready

  for (int kt = 0; kt < nt; ++kt) {
    const int cur = kt & 1;
    if (kt + 1 < nt) stage(cur ^ 1, (kt + 1) << 5);  // in-flight during MFMA

    bf16x8 ah[4], al[4], bh[NR], bl[NR];
#pragma unroll
    for (int m = 0; m < 4; ++m) {
      const int r = wm + m * 16 + fr;
      ah[m] = *reinterpret_cast<const bf16x8*>(&As[cur][0][r][fg * 8]);
      al[m] = *reinterpret_cast<const bf16x8*>(&As[cur][1][r][fg * 8]);
    }
#pragma unroll
    for (int n = 0; n < NR; ++n) {
      const int r = wn + n * 16 + fr;
      bh[n] = *reinterpret_cast<const bf16x8*>(&Bs[cur][0][r][fg * 8]);
      bl[n] = *reinterpret_cast<const bf16x8*>(&Bs[cur][1][r][fg * 8]);
    }
    // C^T fragments: mfma(B, A) (operand-swapped)
#pragma unroll
    for (int m = 0; m < 4; ++m)
#pragma unroll
      for (int n = 0; n < NR; ++n) {
        acc[m][n] = __builtin_amdgcn_mfma_f32_16x16x32_bf16(bh[n], ah[m], acc[m][n], 0, 0, 0);
        acc[m][n] = __builtin_amdgcn_mfma_f32_16x16x32_bf16(bl[n], ah[m], acc[m][n], 0, 0, 0);
        acc[m][n] = __builtin_amdgcn_mfma_f32_16x16x32_bf16(bh[n], al[m], acc[m][n], 0, 0, 0);
      }
    __syncthreads();  // vmcnt(0): next buf ready; lgkm: this buf's reads done
  }

  float* __restrict__ Cw = (s == 0) ? C : C2;
#pragma unroll
  for (int m = 0; m < 4; ++m) {
    const int row = m0 + wm + m * 16 + fr;
#pragma unroll
    for (int n = 0; n < NR; ++n) {
      const int col = n0 + wn + n * 16 + fg * 4;  // 4 consecutive cols
      f32x4 v = acc[m][n];
      if constexpr (EPI != EPI_PART) {
        const f32x4 b4 = *reinterpret_cast<const f32x4*>(bias + col);
#pragma unroll
        for (int c = 0; c < 4; ++c) v[c] += b4[c];
      }
      if constexpr (EPI == EPI_BIAS_RELU) {
#pragma unroll
        for (int c = 0; c < 4; ++c) v[c] = fmaxf(v[c], 0.f);
      }
      if constexpr (EPI == EPI_QKV) {
        if (col < 1024) {  // q|k -> bf16 hi/lo, stride 1024 (uniform per block)
          bf16x4 h, l;
#pragma unroll
          for (int c = 0; c < 4; ++c) {
            const bf16 hh = (bf16)v[c];
            h[c] = hh;
            l[c] = (bf16)(v[c] - (float)hh);
          }
          *reinterpret_cast<bf16x4*>(&Chi[(size_t)row * 1024 + col]) = h;
          *reinterpret_cast<bf16x4*>(&Clo[(size_t)row * 1024 + col]) = l;
        } else {  // v -> f32, stride 512
          *reinterpret_cast<f32x4*>(&C[(size_t)row * D_ + col - 1024]) = v;
        }
      } else if constexpr (SPLIT) {
        bf16x4 h, l;
#pragma unroll
        for (int c = 0; c < 4; ++c) {
          const bf16 hh = (bf16)v[c];
          h[c] = hh;
          l[c] = (bf16)(v[c] - (float)hh);
        }
        *reinterpret_cast<bf16x4*>(&Chi[(size_t)row * ldc + col]) = h;
        *reinterpret_cast<bf16x4*>(&Clo[(size_t)row * ldc + col]) = l;
      } else {
        *reinterpret_cast<f32x4*>(&Cw[(size_t)row * ldc + col]) = v;
      }
    }
  }
}

// ---------------------------------------------------------------------------
// Attention phase 1 (MFMA): one block per causal (i-tile64, j-chunk128) pair
// x (b,h). S = Qhi*Khi^T + Qhi*Klo^T + Qlo*Khi^T via mfma_16x16x32_bf16.
// ---------------------------------------------------------------------------
__global__ __launch_bounds__(256) void attn_part_kernel(
    const bf16* __restrict__ qk_hi, const bf16* __restrict__ qk_lo,
    const int* __restrict__ lengths,
    float* __restrict__ pm, float* __restrict__ pl, float* __restrict__ pd) {
  __shared__ __align__(16) bf16 Qh[64][72], Ql[64][72];
  __shared__ __align__(16) bf16 Kh[64][72], Kl[64][72];
  const int t = threadIdx.x;
  const int lane = t & 63, wv = t >> 6;
  const int fr = lane & 15, fg = lane >> 4;
  const int bh = blockIdx.y;
  const int bb = bh >> 3, h = bh & 7;

  // unflatten p -> (ib, jc): ib=2a starts at a^2+a, ib=2a+1 starts at (a+1)^2
  const int p = blockIdx.x;
  int a = (int)sqrtf((float)p);
  while ((a + 1) * (a + 1) <= p) ++a;
  while (a * a > p) --a;
  int ib, jc;
  if (p >= a * a + a) { ib = 2 * a;     jc = p - (a * a + a); }
  else                { ib = 2 * a - 1; jc = p - a * a; }

  const int i0 = ib * 64;
  const int len = lengths[bb];
  if (i0 >= len || jc * 128 >= len) return;  // block-uniform: partials unread

  const int sr = t >> 2, sc0 = (t & 3) * 16;  // staging: row, 16-elem segment
  {  // stage Q hi/lo tile
    const size_t gb = (size_t)(bb * S_ + i0 + sr) * 1024 + h * DK_ + sc0;
    *reinterpret_cast<int4*>(&Qh[sr][sc0])     = *reinterpret_cast<const int4*>(qk_hi + gb);
    *reinterpret_cast<int4*>(&Qh[sr][sc0 + 8]) = *reinterpret_cast<const int4*>(qk_hi + gb + 8);
    *reinterpret_cast<int4*>(&Ql[sr][sc0])     = *reinterpret_cast<const int4*>(qk_lo + gb);
    *reinterpret_cast<int4*>(&Ql[sr][sc0 + 8]) = *reinterpret_cast<const int4*>(qk_lo + gb + 8);
  }

  float m_r[4], l_r[4], d_r[4];
#pragma unroll
  for (int r = 0; r < 4; ++r) { m_r[r] = -1e30f; l_r[r] = 0.f; d_r[r] = 0.f; }

  const int jlim = min(i0 + 63, len - 1);
  for (int jt = 0; jt < 2; ++jt) {
    const int j0 = jc * 128 + jt * 64;
    if (j0 > jlim) break;  // uniform
    {  // stage K hi/lo tile
      const size_t gb = (size_t)(bb * S_ + j0 + sr) * 1024 + 512 + h * DK_ + sc0;
      *reinterpret_cast<int4*>(&Kh[sr][sc0])     = *reinterpret_cast<const int4*>(qk_hi + gb);
      *reinterpret_cast<int4*>(&Kh[sr][sc0 + 8]) = *reinterpret_cast<const int4*>(qk_hi + gb + 8);
      *reinterpret_cast<int4*>(&Kl[sr][sc0])     = *reinterpret_cast<const int4*>(qk_lo + gb);
      *reinterpret_cast<int4*>(&Kl[sr][sc0 + 8]) = *reinterpret_cast<const int4*>(qk_lo + gb + 8);
    }
    __syncthreads();

    f32x4 sc[4] = {};
#pragma unroll
    for (int kk = 0; kk < 2; ++kk) {
      const bf16x8 qh = *reinterpret_cast<const bf16x8*>(&Qh[wv * 16 + fr][kk * 32 + fg * 8]);
      const bf16x8 ql = *reinterpret_cast<const bf16x8*>(&Ql[wv * 16 + fr][kk * 32 + fg * 8]);
#pragma unroll
      for (int jf = 0; jf < 4; ++jf) {
        const bf16x8 kh = *reinterpret_cast<const bf16x8*>(&Kh[jf * 16 + fr][kk * 32 + fg * 8]);
        const bf16x8 kl = *reinterpret_cast<const bf16x8*>(&Kl[jf * 16 + fr][kk * 32 + fg * 8]);
        sc[jf] = __builtin_amdgcn_mfma_f32_16x16x32_bf16(qh, kh, sc[jf], 0, 0, 0);
        sc[jf] = __builtin_amdgcn_mfma_f32_16x16x32_bf16(qh, kl, sc[jf], 0, 0, 0);
        sc[jf] = __builtin_amdgcn_mfma_f32_16x16x32_bf16(ql, kh, sc[jf], 0, 0, 0);
      }
    }

    // online softmax row-stats update (state redundant across the 16 fr lanes)
#pragma unroll
    for (int r = 0; r < 4; ++r) {
      const int ig = i0 + wv * 16 + fg * 4 + r;
      float s4[4];
      float mx = -1e30f;
#pragma unroll
      for (int jf = 0; jf < 4; ++jf) {
        const int j = j0 + jf * 16 + fr;
        float v = sc[jf][r];
        if (j > ig || j >= len) v = -1e30f;  // causal + padding mask
        s4[jf] = v;
        mx = fmaxf(mx, v);
      }
#pragma unroll
      for (int off = 1; off < 16; off <<= 1) mx = fmaxf(mx, __shfl_xor(mx, off));
      const float mnew = fmaxf(m_r[r], mx);
      float ps = 0.f, pdg = 0.f;
#pragma unroll
      for (int jf = 0; jf < 4; ++jf) {
        const float e = __expf(s4[jf] - mnew);
        ps += e;
        if (j0 + jf * 16 + fr == ig) pdg = e;  // diagonal numerator
      }
#pragma unroll
      for (int off = 1; off < 16; off <<= 1) {
        ps += __shfl_xor(ps, off);
        pdg += __shfl_xor(pdg, off);
      }
      const float scale = __expf(m_r[r] - mnew);
      l_r[r] = l_r[r] * scale + ps;
      d_r[r] = d_r[r] * scale + pdg;
      m_r[r] = mnew;
    }
    __syncthreads();
  }

  if (fr == 0) {  // one lane per row writes partials
    const size_t base = ((size_t)(bh * 32 + ib) * 16 + jc) * 64;
#pragma unroll
    for (int r = 0; r < 4; ++r) {
      const int row = wv * 16 + fg * 4 + r;
      const float mm = m_r[r];
      const bool ok = mm > -1e29f;  // row saw >=1 valid key in this chunk
      pm[base + row] = mm;
      pl[base + row] = ok ? l_r[r] : 0.f;
      pd[base + row] = ok ? d_r[r] : 0.f;
    }
  }
}

// ---------------------------------------------------------------------------
// Attention phase 2: merge partials per (b,h,i-tile), write wgt=(d/l)*v bf16
// ---------------------------------------------------------------------------
__global__ __launch_bounds__(256) void attn_merge_kernel(
    const float* __restrict__ vsrc, const int* __restrict__ lengths,
    const float* __restrict__ pm, const float* __restrict__ pl,
    const float* __restrict__ pd, bf16* __restrict__ whi, bf16* __restrict__ wlo) {
  __shared__ float msh[4][64], lsh[4][64], dsh[4][64];
  __shared__ float dgs[64];
  const int t = threadIdx.x;
  const int ib = blockIdx.x, bh = blockIdx.y;
  const int bb = bh >> 3, h = bh & 7;
  const int i0 = ib * 64;
  const int len = lengths[bb];

  const int r = t & 63, g = t >> 6;
  float m = -1e30f, l = 0.f, d = 0.f;
  if (i0 < len) {  // else partials unread (poison-safe: dg forced 0 below)
    const int jcmax = min((i0 + 63) >> 7, (len - 1) >> 7);
    const size_t base = ((size_t)(bh * 32 + ib) * 16) * 64 + r;
    for (int jc = g; jc <= jcmax; jc += 4) {
      const size_t idx = base + (size_t)jc * 64;
      const float m2 = pm[idx], l2 = pl[idx], d2 = pd[idx];
      const float mn = fmaxf(m, m2);
      const float e1 = __expf(m - mn), e2 = __expf(m2 - mn);
      l = l * e1 + l2 * e2;
      d = d * e1 + d2 * e2;
      m = mn;
    }
  }
  msh[g][r] = m; lsh[g][r] = l; dsh[g][r] = d;
  __syncthreads();
  if (t < 64) {
    float M = msh[0][t], L = lsh[0][t], Dv = dsh[0][t];
#pragma unroll
    for (int gg = 1; gg < 4; ++gg) {
      const float m2 = msh[gg][t], l2 = lsh[gg][t], d2 = dsh[gg][t];
      const float mn = fmaxf(M, m2);
      const float e1 = __expf(M - mn), e2 = __expf(m2 - mn);
      L = L * e1 + l2 * e2;
      Dv = Dv * e1 + d2 * e2;
      M = mn;
    }
    // valid rows always have the jc=0 partial with l >= 1 -> L >= 1
    dgs[t] = (i0 + t < len) ? Dv / L : 0.f;
  }
  __syncthreads();

  const int rr = t >> 2, q = t & 3;
  const float dg = dgs[rr];
  const size_t obase = (size_t)(bb * S_ + i0 + rr) * D_ + h * DK_;
#pragma unroll
  for (int kk = 0; kk < 4; ++kk) {
    const int col = q * 4 + kk * 16;
    const float4 v4 = *reinterpret_cast<const float4*>(vsrc + obase + col);
    const float vv[4] = {dg * v4.x, dg * v4.y, dg * v4.z, dg * v4.w};
    bf16x4 hh, ll;
#pragma unroll
    for (int c = 0; c < 4; ++c) {
      const bf16 x = (bf16)vv[c];
      hh[c] = x;
      ll[c] = (bf16)(vv[c] - (float)x);
    }
    *reinterpret_cast<bf16x4*>(&whi[obase + col]) = hh;
    *reinterpret_cast<bf16x4*>(&wlo[obase + col]) = ll;
  }
}

// ---------------------------------------------------------------------------
// LN1 fused: h1 = P0 + P1 + bo + mask(x); y1 = LN(h1) written as bf16 hi/lo.
// ---------------------------------------------------------------------------
__global__ __launch_bounds__(256) void ln1_fused_kernel(
    const float* __restrict__ P0, const float* __restrict__ P1,
    const float* __restrict__ x, const int* __restrict__ lengths,
    const float* __restrict__ bo,
    const float* __restrict__ gamma, const float* __restrict__ beta,
    bf16* __restrict__ Yhi, bf16* __restrict__ Ylo) {
  const int row = blockIdx.x;
  const int t = threadIdx.x;
  const int lenb = lengths[row >> 11];
  const bool valid = (row & (S_ - 1)) < lenb;
  const size_t ro = (size_t)row * D_ + t * 2;
  const float2 p0 = *reinterpret_cast<const float2*>(P0 + ro);
  const float2 p1 = *reinterpret_cast<const float2*>(P1 + ro);
  const float2 xv = *reinterpret_cast<const float2*>(x + ro);
  const float2 bv = *reinterpret_cast<const float2*>(bo + t * 2);
  float hx = p0.x + p1.x + bv.x + (valid ? xv.x : 0.f);
  float hy = p0.y + p1.y + bv.y + (valid ? xv.y : 0.f);

  float s = hx + hy, s2 = hx * hx + hy * hy;
#pragma unroll
  for (int off = 1; off < 64; off <<= 1) {
    s += __shfl_xor(s, off);
    s2 += __shfl_xor(s2, off);
  }
  __shared__ float red[8];
  const int w = t >> 6;
  if ((t & 63) == 0) { red[w] = s; red[4 + w] = s2; }
  __syncthreads();
  const float ts  = red[0] + red[1] + red[2] + red[3];
  const float ts2 = red[4] + red[5] + red[6] + red[7];
  const float mean = ts * (1.f / D_);
  const float var  = ts2 * (1.f / D_) - mean * mean;
  const float inv  = 1.f / sqrtf(var + EPS_);
  const float2 g  = *reinterpret_cast<const float2*>(gamma + t * 2);
  const float2 bt = *reinterpret_cast<const float2*>(beta + t * 2);
  const float ox = g.x * ((hx - mean) * inv) + bt.x;
  const float oy = g.y * ((hy - mean) * inv) + bt.y;
  const bf16 ohx = (bf16)ox, ohy = (bf16)oy;
  Yhi[ro] = ohx;  Yhi[ro + 1] = ohy;
  Ylo[ro] = (bf16)(ox - (float)ohx);
  Ylo[ro + 1] = (bf16)(oy - (float)ohy);
}

// ---------------------------------------------------------------------------
// LN2 fused: h2 = Q0 + Q1 + b2 + (y1hi+y1lo); out = LN(h2) f32.
// ---------------------------------------------------------------------------
__global__ __launch_bounds__(256) void ln2_fused_kernel(
    const float* __restrict__ Q0, const float* __restrict__ Q1,
    const bf16* __restrict__ Yhi, const bf16* __restrict__ Ylo,
    const float* __restrict__ b2,
    const float* __restrict__ gamma, const float* __restrict__ beta,
    float* __restrict__ out) {
  const int row = blockIdx.x;
  const int t = threadIdx.x;
  const size_t ro = (size_t)row * D_ + t * 2;
  const float2 q0 = *reinterpret_cast<const float2*>(Q0 + ro);
  const float2 q1 = *reinterpret_cast<const float2*>(Q1 + ro);
  const float2 bv = *reinterpret_cast<const float2*>(b2 + t * 2);
  const float y1x = (float)Yhi[ro] + (float)Ylo[ro];
  const float y1y = (float)Yhi[ro + 1] + (float)Ylo[ro + 1];
  float hx = q0.x + q1.x + bv.x + y1x;
  float hy = q0.y + q1.y + bv.y + y1y;

  float s = hx + hy, s2 = hx * hx + hy * hy;
#pragma unroll
  for (int off = 1; off < 64; off <<= 1) {
    s += __shfl_xor(s, off);
    s2 += __shfl_xor(s2, off);
  }
  __shared__ float red[8];
  const int w = t >> 6;
  if ((t & 63) == 0) { red[w] = s; red[4 + w] = s2; }
  __syncthreads();
  const float ts  = red[0] + red[1] + red[2] + red[3];
  const float ts2 = red[4] + red[5] + red[6] + red[7];
  const float mean = ts * (1.f / D_);
  const float var  = ts2 * (1.f / D_) - mean * mean;
  const float inv  = 1.f / sqrtf(var + EPS_);
  const float2 g  = *reinterpret_cast<const float2*>(gamma + t * 2);
  const float2 bt = *reinterpret_cast<const float2*>(beta + t * 2);
  float2 o;
  o.x = g.x * ((hx - mean) * inv) + bt.x;
  o.y = g.y * ((hy - mean) * inv) + bt.y;
  *reinterpret_cast<float2*>(out + ro) = o;
}

// ---------------------------------------------------------------------------
extern "C" void kernel_launch(void* const* d_in, const int* in_sizes, int n_in,
                              void* d_out, int out_size, void* d_ws, size_t ws_size,
                              hipStream_t stream) {
  const float* x       = (const float*)d_in[0];
  const int*   lengths = (const int*)d_in[1];
  const float* Wq = (const float*)d_in[2];
  const float* bq = (const float*)d_in[3];
  const float* Wk = (const float*)d_in[4];
  const float* bk = (const float*)d_in[5];
  const float* Wv = (const float*)d_in[6];
  const float* bv = (const float*)d_in[7];
  const float* Wo = (const float*)d_in[8];
  const float* bo = (const float*)d_in[9];
  const float* W1 = (const float*)d_in[10];
  const float* b1 = (const float*)d_in[11];
  const float* W2 = (const float*)d_in[12];
  const float* b2 = (const float*)d_in[13];
  const float* gamma1 = (const float*)d_in[14];
  const float* beta1  = (const float*)d_in[15];
  const float* gamma2 = (const float*)d_in[16];
  const float* beta2  = (const float*)d_in[17];
  float* out = (float*)d_out;

  char* ws = (char*)d_ws;
  // ---- workspace layout (lifetime-overlapped, < 64 MB) ----
  bf16*  qkvT_hi = (bf16*)(ws + 0);          // [1536][512]
  bf16*  qkvT_lo = (bf16*)(ws + 1572864);
  bf16*  WoT_hi  = (bf16*)(ws + 3145728);    // [512][512]
  bf16*  WoT_lo  = (bf16*)(ws + 3670016);
  bf16*  W1T_hi  = (bf16*)(ws + 4194304);    // [2048][512]
  bf16*  W1T_lo  = (bf16*)(ws + 6291456);
  bf16*  W2T_hi  = (bf16*)(ws + 8388608);    // [512][2048]
  bf16*  W2T_lo  = (bf16*)(ws + 10485760);
  float* bqkv    = (float*)(ws + 12582912);  // [1536]
  // region A: qk hi/lo + v f32 (24MB) -> Wo partials P0/P1 -> ff1 hi/lo
  bf16*  qk_hi   = (bf16*)(ws + 12589056);   // [4096][1024]
  bf16*  qk_lo   = (bf16*)(ws + 20977664);
  float* v_f32   = (float*)(ws + 29366272);  // [4096][512], ends 37754880
  float* P0      = (float*)(ws + 12589056);  // [4096][512] (qk dead after attn_part)
  float* P1      = (float*)(ws + 20977664);
  float* part_m  = (float*)(ws + 37754880);  // attn partials, 6MB window
  float* part_l  = (float*)(ws + 39852032);
  float* part_d  = (float*)(ws + 41949184);  // ends 44046336
  bf16*  ff1_hi  = (bf16*)(ws + 12589056);   // [4096][2048] (after LN1)
  bf16*  ff1_lo  = (bf16*)(ws + 29366272);   // ends 46143488
  // region B: xm hi/lo -> y1 hi/lo (live through LN2)
  bf16*  xm_hi   = (bf16*)(ws + 46143488);   // [4096][512]
  bf16*  xm_lo   = (bf16*)(ws + 50337792);
  bf16*  y1_hi   = (bf16*)(ws + 46143488);
  bf16*  y1_lo   = (bf16*)(ws + 50337792);
  // region C: wgt hi/lo -> FF2 partial Q0
  bf16*  wgt_hi  = (bf16*)(ws + 54532096);   // [4096][512]
  bf16*  wgt_lo  = (bf16*)(ws + 58726400);   // ends 62920704
  float* Q0      = (float*)(ws + 54532096);  // (after Wo)
  // FF2 partial Q1 over dead qkvT/WoT/W1T weights (after FF1):
  float* Q1      = (float*)(ws + 0);         // [4096][512] = 8.4MB, ends 8388608

  const dim3 blk(256);
  const int M = B_ * S_;  // 4096

  // 1) fused prep: all weight transposes + bias pack + mask/split (1 launch)
  PrepArgs pa;
  pa.w[0] = Wq; pa.w[1] = Wk; pa.w[2] = Wv; pa.w[3] = Wo;
  pa.thi[0] = qkvT_hi; pa.thi[1] = qkvT_hi; pa.thi[2] = qkvT_hi; pa.thi[3] = WoT_hi;
  pa.tlo[0] = qkvT_lo; pa.tlo[1] = qkvT_lo; pa.tlo[2] = qkvT_lo; pa.tlo[3] = WoT_lo;
  pa.rowOff[0] = 0; pa.rowOff[1] = 512; pa.rowOff[2] = 1024; pa.rowOff[3] = 0;
  pa.W1 = W1; pa.W1hi = W1T_hi; pa.W1lo = W1T_lo;
  pa.W2 = W2; pa.W2hi = W2T_hi; pa.W2lo = W2T_lo;
  pa.x = x; pa.lengths = lengths; pa.xhi = xm_hi; pa.xlo = xm_lo;
  pa.bq = bq; pa.bk = bk; pa.bv = bv; pa.bqkv = bqkv;
  prep_kernel<<<dim3(5126), blk, 0, stream>>>(pa);

  // 2) fused QKV GEMM -> qk hi/lo (bf16) + v (f32).  grid 32x24 = 768
  gemm_kernel<EPI_QKV, false, 64><<<dim3(768), blk, 0, stream>>>(
      xm_hi, xm_lo, qkvT_hi, qkvT_lo, bqkv,
      v_f32, nullptr, qk_hi, qk_lo, 512, QS_, 24, 768, 512);

  // 3) attention: MFMA partials (272 causal pairs x 16 bh) + merge
  attn_part_kernel<<<dim3(272, 16), blk, 0, stream>>>(qk_hi, qk_lo, lengths,
                                                      part_m, part_l, part_d);
  attn_merge_kernel<<<dim3(32, 16), blk, 0, stream>>>(v_f32, lengths, part_m, part_l, part_d,
                                                      wgt_hi, wgt_lo);

  // 4) O-proj split-K=2 partials.  grid 2x32x8 = 512
  gemm_kernel<EPI_PART, false, 64><<<dim3(512), blk, 0, stream>>>(
      wgt_hi, wgt_lo, WoT_hi, WoT_lo, nullptr,
      P0, P1, nullptr, nullptr, 512, D_, 8, 256, 256);

  // 5) LN1 fused (P0+P1+bo+mask(x)) -> y1 hi/lo
  ln1_fused_kernel<<<dim3(M), blk, 0, stream>>>(P0, P1, x, lengths, bo,
                                                gamma1, beta1, y1_hi, y1_lo);

  // 6) FF1 (+bias+relu) -> ff1 hi/lo.  grid 32x32 = 1024
  gemm_kernel<EPI_BIAS_RELU, true, 64><<<dim3(1024), blk, 0, stream>>>(
      y1_hi, y1_lo, W1T_hi, W1T_lo, b1,
      nullptr, nullptr, ff1_hi, ff1_lo, 512, FF_, 32, 1024, 512);

  // 7) FF2 split-K=2 partials.  grid 2x32x8 = 512
  gemm_kernel<EPI_PART, false, 64><<<dim3(512), blk, 0, stream>>>(
      ff1_hi, ff1_lo, W2T_hi, W2T_lo, nullptr,
      Q0, Q1, nullptr, nullptr, FF_, D_, 8, 256, 1024);

  // 8) LN2 fused (Q0+Q1+b2+y1) -> out
  ln2_fused_kernel<<<dim3(M), blk, 0, stream>>>(Q0, Q1, y1_hi, y1_lo, b2,
                                                gamma2, beta2, out);
}